// Round 10
// baseline (681.142 us; speedup 1.0000x reference)
//
#include <hip/hip_runtime.h>
#include <hip/hip_bf16.h>

// ---------------------------------------------------------------------------
// GraphSAGE forward on MI355X — round 13.
// Post-mortem of round 12: bucketize ran at 2.9% occupancy (64 blocks on 256
// CUs) -> 211us. The bucketing machinery itself was correct (passed; WRITE
// 12.5MB sequential). Fix: full-parallel phase A.
//   * es rounded to a multiple of 256 -> each 256-edge block lies in ONE
//     slice; phase A launches at edge-grid width (6272 blocks).
//   * slot assignment via global atomic cursors = the scanned per-(c,s)
//     bases (stot), one wave-ballot-aggregated atomicAdd per (wave,chunk):
//     ~200K atomics over 512 counters 256B apart.
//   * phase B unchanged: bid%8==chunk pins each chunk's esrc window writers
//     to one XCD -> sector writes coalesce in its L2.
// Aggregate x3 (172us) remains at its structural floor (do not re-tune).
// ---------------------------------------------------------------------------

typedef __attribute__((ext_vector_type(8))) short short8v;   // 8 x bf16 (4 VGPRs)
typedef __attribute__((ext_vector_type(4))) float f32x4;

#define RK_CH 12544   // nodes per dst-chunk (50,176 B LDS histogram)
#define RK_NS 64      // edge slices

__device__ __forceinline__ unsigned short f2bf(float f) {
    __hip_bfloat16 h = __float2bfloat16(f);
    return *reinterpret_cast<unsigned short*>(&h);
}
__device__ __forceinline__ float bf_lo(unsigned u) { return __uint_as_float(u << 16); }
__device__ __forceinline__ float bf_hi(unsigned u) { return __uint_as_float(u & 0xffff0000u); }
__device__ __forceinline__ unsigned packbf(float lo, float hi) {
    return ((unsigned)f2bf(hi) << 16) | f2bf(lo);
}

// ---------------- fused pre-pass: rank_hist(+stot) | cvt(x) | cvt6(weights) -

__launch_bounds__(256)
__global__ void pre_kernel(const int* __restrict__ dst,
                           unsigned short* __restrict__ rank16,
                           unsigned short* __restrict__ counts16,
                           unsigned* __restrict__ stot,
                           int nE, int nChunk, int es,
                           const float* __restrict__ x, unsigned short* __restrict__ xbf, int x4,
                           const float* __restrict__ w0, const float* __restrict__ w1,
                           const float* __restrict__ w2, const float* __restrict__ w3,
                           const float* __restrict__ w4, const float* __restrict__ w5,
                           unsigned short* __restrict__ o0, unsigned short* __restrict__ o1,
                           unsigned short* __restrict__ o2, unsigned short* __restrict__ o3,
                           unsigned short* __restrict__ o4, unsigned short* __restrict__ o5,
                           int w4n, int w4b) {
    __shared__ unsigned cnt[RK_CH];
    __shared__ unsigned red[256];
    int rhB  = nChunk * RK_NS;
    int cvtB = (x4 + 255) / 256;
    int bid  = blockIdx.x;

    if (bid < rhB) {
        // ---- rank_hist ----
        int s = bid / nChunk;   // consecutive blocks share the dst slice
        int c = bid % nChunk;
        int lo = c * RK_CH;
        for (int i = threadIdx.x; i < RK_CH; i += 256) cnt[i] = 0u;
        __syncthreads();

        int ebeg = s * es;
        int eend = ebeg + es; if (eend > nE) eend = nE;
        if (ebeg < eend) {
            int nvec = (eend - ebeg) >> 2;   // es multiple of 256, dst 16B-aligned
            for (int g = threadIdx.x; g < nvec; g += 256) {
                int e = ebeg + g * 4;
                int4 d4 = *(const int4*)&dst[e];
                unsigned dc;
                dc = (unsigned)(d4.x - lo);
                if (dc < RK_CH) rank16[e]     = (unsigned short)atomicAdd(&cnt[dc], 1u);
                dc = (unsigned)(d4.y - lo);
                if (dc < RK_CH) rank16[e + 1] = (unsigned short)atomicAdd(&cnt[dc], 1u);
                dc = (unsigned)(d4.z - lo);
                if (dc < RK_CH) rank16[e + 2] = (unsigned short)atomicAdd(&cnt[dc], 1u);
                dc = (unsigned)(d4.w - lo);
                if (dc < RK_CH) rank16[e + 3] = (unsigned short)atomicAdd(&cnt[dc], 1u);
            }
            for (int e = ebeg + (nvec << 2) + threadIdx.x; e < eend; e += 256) {
                unsigned dc = (unsigned)(dst[e] - lo);
                if (dc < RK_CH) rank16[e] = (unsigned short)atomicAdd(&cnt[dc], 1u);
            }
        }
        __syncthreads();
        size_t base = ((size_t)(c * RK_NS + s)) * RK_CH;
        unsigned tsum = 0;
        for (int i = threadIdx.x; i < RK_CH; i += 256) {
            counts16[base + i] = (unsigned short)cnt[i];
            tsum += cnt[i];
        }
        red[threadIdx.x] = tsum;
        __syncthreads();
        #pragma unroll
        for (int off = 128; off >= 1; off >>= 1) {
            if (threadIdx.x < off) red[threadIdx.x] += red[threadIdx.x + off];
            __syncthreads();
        }
        if (threadIdx.x == 0) stot[(c << 6) | s] = red[0];
    } else if (bid < rhB + cvtB) {
        // ---- cvt x ----
        int i = (bid - rhB) * 256 + threadIdx.x;
        if (i < x4) {
            float4 v = ((const float4*)x)[i];
            ushort4 o;
            o.x = f2bf(v.x); o.y = f2bf(v.y); o.z = f2bf(v.z); o.w = f2bf(v.w);
            ((ushort4*)xbf)[i] = o;
        }
    } else {
        // ---- cvt6 weights ----
        int idx  = bid - rhB - cvtB;
        int wsel = idx / w4b;
        int wb   = idx % w4b;
        const float* in; unsigned short* out;
        switch (wsel) {
            case 0: in = w0; out = o0; break;
            case 1: in = w1; out = o1; break;
            case 2: in = w2; out = o2; break;
            case 3: in = w3; out = o3; break;
            case 4: in = w4; out = o4; break;
            default: in = w5; out = o5; break;
        }
        int i = wb * 256 + threadIdx.x;
        if (i < w4n) {
            float4 v = ((const float4*)in)[i];
            ushort4 o;
            o.x = f2bf(v.x); o.y = f2bf(v.y); o.z = f2bf(v.z); o.w = f2bf(v.w);
            ((ushort4*)out)[i] = o;
        }
    }
}

// ---------------- seg_offsets + scan1 fused ----------------

__launch_bounds__(1024)
__global__ void seg_scan1_kernel(unsigned short* __restrict__ counts16,
                                 int* __restrict__ rowptr, int* __restrict__ bsum, int n) {
    __shared__ int s[1024];
    int lid = threadIdx.x;
    int d = blockIdx.x * 1024 + lid;
    int v = 0;
    if (d < n) {
        int c = d / RK_CH;
        int i = d - c * RK_CH;
        size_t base = ((size_t)c * RK_NS) * RK_CH + i;
        unsigned run = 0;
        for (int sl = 0; sl < RK_NS; ++sl) {
            size_t idx = base + (size_t)sl * RK_CH;
            unsigned t = counts16[idx];
            counts16[idx] = (unsigned short)run;
            run += t;
        }
        v = (int)run;
    }
    s[lid] = v;
    __syncthreads();
    #pragma unroll
    for (int off = 1; off < 1024; off <<= 1) {
        int t = (lid >= off) ? s[lid - off] : 0;
        __syncthreads();
        s[lid] += t;
        __syncthreads();
    }
    if (d < n) rowptr[d] = s[lid] - v;
    if (lid == 0) bsum[blockIdx.x] = s[1023];
}

// block 0: exclusive-ize bsum[nb]; block 1: exclusive scan stot[ns] in place
// (scanned stot then serves as the phase-A bucket cursors).
__launch_bounds__(1024)
__global__ void scans2b_kernel(int* __restrict__ bsum, int nb,
                               unsigned* __restrict__ stot, int ns) {
    __shared__ int s[1024];
    int lid = threadIdx.x;
    if (blockIdx.x == 0) {
        int v = (lid < nb) ? bsum[lid] : 0;
        s[lid] = v;
        __syncthreads();
        #pragma unroll
        for (int off = 1; off < 1024; off <<= 1) {
            int t = (lid >= off) ? s[lid - off] : 0;
            __syncthreads();
            s[lid] += t;
            __syncthreads();
        }
        if (lid < nb) bsum[lid] = s[lid] - v;
    } else {
        int v = (lid < ns) ? (int)stot[lid] : 0;
        s[lid] = v;
        __syncthreads();
        #pragma unroll
        for (int off = 1; off < 1024; off <<= 1) {
            int t = (lid >= off) ? s[lid - off] : 0;
            __syncthreads();
            s[lid] += t;
            __syncthreads();
        }
        if (lid < ns) stot[lid] = (unsigned)(s[lid] - v);
    }
}

__global__ void scan3_kernel(int* __restrict__ rowptr, const int* __restrict__ bsum,
                             int n, int nE) {
    int i = blockIdx.x * blockDim.x + threadIdx.x;
    if (i < n) rowptr[i] += bsum[i >> 10];
    if (i == 0) rowptr[n] = nE;
}

// ---------------- two-phase scatter ----------------
// Phase A (full edge grid): each 256-edge block lies in ONE slice (es % 256
// == 0). Compute each edge's FINAL esrc position; append (pos,src) to the
// (chunk,slice) bucket region. Slots via wave-ballot + one leader atomicAdd
// on the scanned-stot cursor per (wave,chunk). Bucket order within a region
// is nondeterministic — irrelevant, pos is exact.
__launch_bounds__(256)
__global__ void bucketize_kernel(const int* __restrict__ src, const int* __restrict__ dst,
                                 const unsigned short* __restrict__ rank16,
                                 const unsigned short* __restrict__ counts16,
                                 const int* __restrict__ rowptr,
                                 unsigned* __restrict__ cursor,   // scanned stot (destructive)
                                 uint2* __restrict__ bkt,
                                 int nE, int nChunk, int es) {
    int e0   = blockIdx.x * 256;
    int e    = e0 + threadIdx.x;
    int s    = e0 / es;                  // uniform within block
    int lane = threadIdx.x & 63;
    bool valid = e < nE;
    int c = 0, pos = 0, srcv = 0;
    if (valid) {
        int d = dst[e];
        srcv = src[e];
        c = (int)((unsigned)d / RK_CH);
        int i = d - c * RK_CH;
        pos = rowptr[d] + (int)counts16[((size_t)((c << 6) | s)) * RK_CH + i]
                        + (int)rank16[e];
    }
    for (int k = 0; k < nChunk; ++k) {
        unsigned long long mask = __ballot(valid && (c == k));
        if (mask) {
            int leader = __ffsll((long long)mask) - 1;
            unsigned wb = 0;
            if (lane == leader)
                wb = atomicAdd(&cursor[(k << 6) | s], (unsigned)__popcll(mask));
            wb = __shfl(wb, leader);
            if (valid && c == k) {
                unsigned slot = wb + (unsigned)__popcll(mask & ((1ull << lane) - 1ull));
                bkt[(size_t)slot] = make_uint2((unsigned)pos, (unsigned)srcv);
            }
        }
    }
}

// Phase B: bid % nChunk == chunk -> all writers of chunk c's esrc window on
// one XCD (round-robin bid->XCD heuristic; correctness mapping-independent).
// Chunk c's bucket region is [rowptr[c*RK_CH], rowptr[min((c+1)*RK_CH, n)]).
__launch_bounds__(256)
__global__ void scatter_b_kernel(const uint2* __restrict__ bkt,
                                 const int* __restrict__ rowptr,
                                 int* __restrict__ esrc, int n, int nChunk, int M) {
    int c = blockIdx.x % nChunk;
    int m = blockIdx.x / nChunk;
    int nlo = c * RK_CH;
    int nhi = (c + 1) * RK_CH; if (nhi > n) nhi = n;
    unsigned lo = (unsigned)rowptr[nlo];
    unsigned hi = (unsigned)rowptr[nhi];
    unsigned csize = hi - lo;
    unsigned seg = (csize + (unsigned)M - 1) / (unsigned)M;
    unsigned b0 = lo + (unsigned)m * seg;
    unsigned b1 = b0 + seg; if (b1 > hi) b1 = hi;
    for (unsigned p = b0 + threadIdx.x; p < b1; p += 256) {
        uint2 pr = bkt[(size_t)p];
        esrc[pr.x] = (int)pr.y;
    }
}

// ---------------- aggregation ----------------
// NOTE (r9/r10): at structural floor (~178MB beyond-L2 traffic). Do not re-tune.

#define ACC8(v) do { \
    s0 += bf_lo((v).x); s1 += bf_hi((v).x); s2 += bf_lo((v).y); s3 += bf_hi((v).y); \
    s4 += bf_lo((v).z); s5 += bf_hi((v).z); s6 += bf_lo((v).w); s7 += bf_hi((v).w); } while (0)

__global__ void aggregate_kernel(const unsigned short* __restrict__ h,
                                 const int* __restrict__ rowptr,
                                 const int* __restrict__ esrc,
                                 unsigned short* __restrict__ agg, int n) {
    int wave = (blockIdx.x * blockDim.x + threadIdx.x) >> 6;
    int lane = threadIdx.x & 63;
    int q    = lane >> 4;           // which node within the wave
    int li   = lane & 15;
    int c0   = li * 8;              // 8 cols owned by this lane
    int node = wave * 4 + q;

    int beg = 0, end = 0;
    if (node < n) { beg = rowptr[node]; end = rowptr[node + 1]; }

    float s0=0.f,s1=0.f,s2=0.f,s3=0.f,s4=0.f,s5=0.f,s6=0.f,s7=0.f;
    int j = beg;
    for (; j + 4 <= end; j += 4) {
        int r0 = esrc[j], r1 = esrc[j + 1], r2 = esrc[j + 2], r3 = esrc[j + 3];
        uint4 v0 = *(const uint4*)&h[(size_t)r0 * 128 + c0];
        uint4 v1 = *(const uint4*)&h[(size_t)r1 * 128 + c0];
        uint4 v2 = *(const uint4*)&h[(size_t)r2 * 128 + c0];
        uint4 v3 = *(const uint4*)&h[(size_t)r3 * 128 + c0];
        ACC8(v0); ACC8(v1); ACC8(v2); ACC8(v3);
    }
    for (; j < end; ++j) {
        int r0 = esrc[j];
        uint4 v0 = *(const uint4*)&h[(size_t)r0 * 128 + c0];
        ACC8(v0);
    }
    if (node < n) {
        int cnt = end - beg;
        float inv = 1.0f / (float)(cnt > 1 ? cnt : 1);
        uint4 o;
        o.x = packbf(s0 * inv, s1 * inv);
        o.y = packbf(s2 * inv, s3 * inv);
        o.z = packbf(s4 * inv, s5 * inv);
        o.w = packbf(s6 * inv, s7 * inv);
        *(uint4*)&agg[(size_t)node * 128 + c0] = o;
    }
}

// ---------------- fused SAGE GEMM via MFMA ----------------

__launch_bounds__(256)
__global__ void sage_gemm_mfma(const unsigned short* __restrict__ A,
                               const unsigned short* __restrict__ H,
                               const unsigned short* __restrict__ Wl,
                               const unsigned short* __restrict__ Wr,
                               const float* __restrict__ bl,
                               unsigned short* __restrict__ out, int n, int relu) {
    int tid  = threadIdx.x;
    int lane = tid & 63;
    int w    = tid >> 6;
    int wm   = w >> 1, wn = w & 1;
    int br   = blockIdx.x * 128 + wm * 64;
    int bc   = wn * 64;
    int lrow = lane & 15;
    int lk   = (lane >> 4) * 8;

    f32x4 acc[4][4] = {};

    #pragma unroll
    for (int half = 0; half < 2; ++half) {
        const unsigned short* X = half ? H : A;
        const unsigned short* W = half ? Wr : Wl;
        const unsigned short* xp[4];
        const unsigned short* wp[4];
        #pragma unroll
        for (int mb = 0; mb < 4; ++mb) {
            int r = br + mb * 16 + lrow;
            if (r >= n) r = n - 1;
            xp[mb] = X + (size_t)r * 128 + lk;
        }
        #pragma unroll
        for (int nb = 0; nb < 4; ++nb)
            wp[nb] = W + (size_t)(bc + nb * 16 + lrow) * 128 + lk;

        #pragma unroll
        for (int ks = 0; ks < 4; ++ks) {
            short8v a[4], b[4];
            #pragma unroll
            for (int mb = 0; mb < 4; ++mb) a[mb] = *(const short8v*)(xp[mb] + ks * 32);
            #pragma unroll
            for (int nb = 0; nb < 4; ++nb) b[nb] = *(const short8v*)(wp[nb] + ks * 32);
            #pragma unroll
            for (int mb = 0; mb < 4; ++mb)
                #pragma unroll
                for (int nb = 0; nb < 4; ++nb)
                    acc[mb][nb] = __builtin_amdgcn_mfma_f32_16x16x32_bf16(
                        a[mb], b[nb], acc[mb][nb], 0, 0, 0);
        }
    }

    int ccol  = lane & 15;
    int crow4 = (lane >> 4) * 4;
    float bv[4];
    #pragma unroll
    for (int nb = 0; nb < 4; ++nb) bv[nb] = bl[bc + nb * 16 + ccol];

    #pragma unroll
    for (int mb = 0; mb < 4; ++mb) {
        #pragma unroll
        for (int r = 0; r < 4; ++r) {
            int row = br + mb * 16 + crow4 + r;
            if (row < n) {
                #pragma unroll
                for (int nb = 0; nb < 4; ++nb) {
                    int col = bc + nb * 16 + ccol;
                    float v = acc[mb][nb][r] + bv[nb];
                    if (relu && v < 0.f) v = 0.f;
                    out[(size_t)row * 128 + col] = f2bf(v);
                }
            }
        }
    }
}

// ---------------- pool + head (fused) ----------------

__device__ __forceinline__ int lbound(const int* __restrict__ a, int n, int v) {
    int lo = 0, hi = n;
    while (lo < hi) { int m = (lo + hi) >> 1; if (a[m] < v) lo = m + 1; else hi = m; }
    return lo;
}

__launch_bounds__(1024)
__global__ void pool_head_kernel(const unsigned short* __restrict__ h,
                                 const int* __restrict__ batch,
                                 const float* __restrict__ Wlin,
                                 const float* __restrict__ blin,
                                 float* __restrict__ out, int n) {
    __shared__ float red[16][128];
    int b  = blockIdx.x;
    int rg = threadIdx.x >> 6;
    int cp = threadIdx.x & 63;
    int lo = lbound(batch, n, b);
    int hi = lbound(batch, n, b + 1);
    float s0 = 0.f, s1 = 0.f;
    for (int i = lo + rg; i < hi; i += 16) {
        unsigned v = *(const unsigned*)&h[(size_t)i * 128 + cp * 2];
        s0 += bf_lo(v); s1 += bf_hi(v);
    }
    red[rg][cp * 2]     = s0;
    red[rg][cp * 2 + 1] = s1;
    __syncthreads();
    #pragma unroll
    for (int off = 8; off >= 1; off >>= 1) {
        if (rg < off) {
            red[rg][cp * 2]     += red[rg + off][cp * 2];
            red[rg][cp * 2 + 1] += red[rg + off][cp * 2 + 1];
        }
        __syncthreads();
    }
    if (threadIdx.x < 32) {
        int j = threadIdx.x;
        int cnt = hi - lo;
        float inv = 1.0f / (float)(cnt > 1 ? cnt : 1);
        const float* wr = &Wlin[(size_t)j * 128];
        float s = 0.f;
        #pragma unroll 4
        for (int c = 0; c < 128; ++c) s += red[0][c] * wr[c];
        out[(size_t)b * 32 + j] = blin[j] + s * inv;
    }
}

extern "C" void kernel_launch(void* const* d_in, const int* in_sizes, int n_in,
                              void* d_out, int out_size, void* d_ws, size_t ws_size,
                              hipStream_t stream) {
    const float* x      = (const float*)d_in[0];
    const int*   eidx   = (const int*)d_in[1];
    const int*   batch  = (const int*)d_in[2];
    const float* Wl[3]  = {(const float*)d_in[3], (const float*)d_in[6], (const float*)d_in[9]};
    const float* bl[3]  = {(const float*)d_in[4], (const float*)d_in[7], (const float*)d_in[10]};
    const float* Wr[3]  = {(const float*)d_in[5], (const float*)d_in[8], (const float*)d_in[11]};
    const float* Wlin   = (const float*)d_in[12];
    const float* blin   = (const float*)d_in[13];
    float* out = (float*)d_out;

    const int N = in_sizes[0] / 128;
    const int E = in_sizes[1] / 2;

    const int* esrc_in = eidx;
    const int* edst_in = eidx + E;

    char* w = (char*)d_ws;
    auto carve = [&](size_t bytes) { char* p = w; w += (bytes + 255) & ~(size_t)255; return p; };
    unsigned short* xbf  = (unsigned short*)carve((size_t)N * 128 * 2);
    unsigned short* hA   = (unsigned short*)carve((size_t)N * 128 * 2);
    unsigned short* hB   = (unsigned short*)carve((size_t)N * 128 * 2);
    unsigned short* agg  = (unsigned short*)carve((size_t)N * 128 * 2);
    unsigned short* Wbf[6];
    for (int i = 0; i < 6; ++i) Wbf[i] = (unsigned short*)carve((size_t)128 * 128 * 2);
    int*   rowptr = (int*)carve((size_t)(N + 1) * 4);
    int*   bsum   = (int*)carve(1024 * 4);
    int*   esrc   = (int*)carve((size_t)E * 4);
    unsigned short* rank16   = (unsigned short*)carve((size_t)E * 2);
    int nChunk = (N + RK_CH - 1) / RK_CH;
    unsigned short* counts16 = (unsigned short*)carve((size_t)nChunk * RK_NS * RK_CH * 2);
    unsigned* stot = (unsigned*)carve(1024 * 4);            // (c<<6)|s totals -> scanned bases -> cursors
    uint2*    bkt  = (uint2*)carve((size_t)E * 8);          // (pos, src) staging
    (void)ws_size; (void)n_in;

    // --- fused pre-pass: rank_hist(+stot) | cvt x | cvt weights ---
    int es = (((E + RK_NS - 1) / RK_NS) + 255) & ~255;   // slice size, multiple of 256
    int x4   = N * 128 / 4;
    int cvtB = (x4 + 255) / 256;
    int w4n  = 128 * 128 / 4;
    int w4b  = (w4n + 255) / 256;
    int rhB  = nChunk * RK_NS;
    hipLaunchKernelGGL(pre_kernel, dim3(rhB + cvtB + 6 * w4b), dim3(256), 0, stream,
                       edst_in, rank16, counts16, stot, E, nChunk, es,
                       x, xbf, x4,
                       Wl[0], Wr[0], Wl[1], Wr[1], Wl[2], Wr[2],
                       Wbf[0], Wbf[1], Wbf[2], Wbf[3], Wbf[4], Wbf[5],
                       w4n, w4b);

    // --- offsets + scans + two-phase scatter ---
    int nchunks = (N + 1023) / 1024;
    hipLaunchKernelGGL(seg_scan1_kernel, dim3(nchunks), dim3(1024), 0, stream,
                       counts16, rowptr, bsum, N);
    hipLaunchKernelGGL(scans2b_kernel, dim3(2), dim3(1024), 0, stream,
                       bsum, nchunks, stot, nChunk * RK_NS);
    int ngrid = (N + 255) / 256;
    hipLaunchKernelGGL(scan3_kernel, dim3(ngrid), dim3(256), 0, stream, rowptr, bsum, N, E);
    int egrid = (E + 255) / 256;
    hipLaunchKernelGGL(bucketize_kernel, dim3(egrid), dim3(256), 0, stream,
                       esrc_in, edst_in, rank16, counts16, rowptr, stot, bkt, E, nChunk, es);
    const int MB = 64;
    hipLaunchKernelGGL(scatter_b_kernel, dim3(nChunk * MB), dim3(256), 0, stream,
                       bkt, rowptr, esrc, N, nChunk, MB);

    // --- 3 SAGE layers ---
    int agrid = (N + 15) / 16;   // 16 nodes per 256-thread block (4 per wave)
    int ggrid = (N + 127) / 128;
    const unsigned short* hin = xbf;
    unsigned short* houts[3] = {hA, hB, hA};
    for (int l = 0; l < 3; ++l) {
        hipLaunchKernelGGL(aggregate_kernel, dim3(agrid), dim3(256), 0, stream,
                           hin, rowptr, esrc, agg, N);
        hipLaunchKernelGGL(sage_gemm_mfma, dim3(ggrid), dim3(256), 0, stream,
                           agg, hin, Wbf[2*l], Wbf[2*l+1], bl[l], houts[l], N, (l < 2) ? 1 : 0);
        hin = houts[l];
    }

    // --- pool + head (fused) ---
    int G = out_size / 32;
    hipLaunchKernelGGL(pool_head_kernel, dim3(G), dim3(1024), 0, stream,
                       hin, batch, Wlin, blin, out, N);
}

// Round 11
// 405.175 us; speedup vs baseline: 1.6811x; 1.6811x over previous
//
#include <hip/hip_runtime.h>
#include <hip/hip_bf16.h>

// ---------------------------------------------------------------------------
// GraphSAGE forward on MI355X — round 14.
// Post-mortem of round 13: bucketize at 78% occupancy / 2.3% VALU / 2.8% HBM
// = pure atomic stall. Root cause: 512 cursors packed into 2KB -> 32 cursors
// per 128B line -> memory-side same-line RMW serialization (~16 domains for
// 200K atomics ~= 335us). Fix: pad each cursor to its own 128B line (stride
// 32 u32, 64KB). Everything else identical to r13 (passed -> machinery OK).
// Pre-commit: if bucketize+scatter_b > ~45us, revert to r11 scatter2.
// ---------------------------------------------------------------------------

typedef __attribute__((ext_vector_type(8))) short short8v;   // 8 x bf16 (4 VGPRs)
typedef __attribute__((ext_vector_type(4))) float f32x4;

#define RK_CH 12544   // nodes per dst-chunk (50,176 B LDS histogram)
#define RK_NS 64      // edge slices
#define CUR_STRIDE 32 // one cursor per 128B line

__device__ __forceinline__ unsigned short f2bf(float f) {
    __hip_bfloat16 h = __float2bfloat16(f);
    return *reinterpret_cast<unsigned short*>(&h);
}
__device__ __forceinline__ float bf_lo(unsigned u) { return __uint_as_float(u << 16); }
__device__ __forceinline__ float bf_hi(unsigned u) { return __uint_as_float(u & 0xffff0000u); }
__device__ __forceinline__ unsigned packbf(float lo, float hi) {
    return ((unsigned)f2bf(hi) << 16) | f2bf(lo);
}

// ---------------- fused pre-pass: rank_hist(+stot) | cvt(x) | cvt6(weights) -

__launch_bounds__(256)
__global__ void pre_kernel(const int* __restrict__ dst,
                           unsigned short* __restrict__ rank16,
                           unsigned short* __restrict__ counts16,
                           unsigned* __restrict__ stot,
                           int nE, int nChunk, int es,
                           const float* __restrict__ x, unsigned short* __restrict__ xbf, int x4,
                           const float* __restrict__ w0, const float* __restrict__ w1,
                           const float* __restrict__ w2, const float* __restrict__ w3,
                           const float* __restrict__ w4, const float* __restrict__ w5,
                           unsigned short* __restrict__ o0, unsigned short* __restrict__ o1,
                           unsigned short* __restrict__ o2, unsigned short* __restrict__ o3,
                           unsigned short* __restrict__ o4, unsigned short* __restrict__ o5,
                           int w4n, int w4b) {
    __shared__ unsigned cnt[RK_CH];
    __shared__ unsigned red[256];
    int rhB  = nChunk * RK_NS;
    int cvtB = (x4 + 255) / 256;
    int bid  = blockIdx.x;

    if (bid < rhB) {
        // ---- rank_hist ----
        int s = bid / nChunk;   // consecutive blocks share the dst slice
        int c = bid % nChunk;
        int lo = c * RK_CH;
        for (int i = threadIdx.x; i < RK_CH; i += 256) cnt[i] = 0u;
        __syncthreads();

        int ebeg = s * es;
        int eend = ebeg + es; if (eend > nE) eend = nE;
        if (ebeg < eend) {
            int nvec = (eend - ebeg) >> 2;   // es multiple of 256, dst 16B-aligned
            for (int g = threadIdx.x; g < nvec; g += 256) {
                int e = ebeg + g * 4;
                int4 d4 = *(const int4*)&dst[e];
                unsigned dc;
                dc = (unsigned)(d4.x - lo);
                if (dc < RK_CH) rank16[e]     = (unsigned short)atomicAdd(&cnt[dc], 1u);
                dc = (unsigned)(d4.y - lo);
                if (dc < RK_CH) rank16[e + 1] = (unsigned short)atomicAdd(&cnt[dc], 1u);
                dc = (unsigned)(d4.z - lo);
                if (dc < RK_CH) rank16[e + 2] = (unsigned short)atomicAdd(&cnt[dc], 1u);
                dc = (unsigned)(d4.w - lo);
                if (dc < RK_CH) rank16[e + 3] = (unsigned short)atomicAdd(&cnt[dc], 1u);
            }
            for (int e = ebeg + (nvec << 2) + threadIdx.x; e < eend; e += 256) {
                unsigned dc = (unsigned)(dst[e] - lo);
                if (dc < RK_CH) rank16[e] = (unsigned short)atomicAdd(&cnt[dc], 1u);
            }
        }
        __syncthreads();
        size_t base = ((size_t)(c * RK_NS + s)) * RK_CH;
        unsigned tsum = 0;
        for (int i = threadIdx.x; i < RK_CH; i += 256) {
            counts16[base + i] = (unsigned short)cnt[i];
            tsum += cnt[i];
        }
        red[threadIdx.x] = tsum;
        __syncthreads();
        #pragma unroll
        for (int off = 128; off >= 1; off >>= 1) {
            if (threadIdx.x < off) red[threadIdx.x] += red[threadIdx.x + off];
            __syncthreads();
        }
        if (threadIdx.x == 0) stot[(c << 6) | s] = red[0];
    } else if (bid < rhB + cvtB) {
        // ---- cvt x ----
        int i = (bid - rhB) * 256 + threadIdx.x;
        if (i < x4) {
            float4 v = ((const float4*)x)[i];
            ushort4 o;
            o.x = f2bf(v.x); o.y = f2bf(v.y); o.z = f2bf(v.z); o.w = f2bf(v.w);
            ((ushort4*)xbf)[i] = o;
        }
    } else {
        // ---- cvt6 weights ----
        int idx  = bid - rhB - cvtB;
        int wsel = idx / w4b;
        int wb   = idx % w4b;
        const float* in; unsigned short* out;
        switch (wsel) {
            case 0: in = w0; out = o0; break;
            case 1: in = w1; out = o1; break;
            case 2: in = w2; out = o2; break;
            case 3: in = w3; out = o3; break;
            case 4: in = w4; out = o4; break;
            default: in = w5; out = o5; break;
        }
        int i = wb * 256 + threadIdx.x;
        if (i < w4n) {
            float4 v = ((const float4*)in)[i];
            ushort4 o;
            o.x = f2bf(v.x); o.y = f2bf(v.y); o.z = f2bf(v.z); o.w = f2bf(v.w);
            ((ushort4*)out)[i] = o;
        }
    }
}

// ---------------- seg_offsets + scan1 fused ----------------

__launch_bounds__(1024)
__global__ void seg_scan1_kernel(unsigned short* __restrict__ counts16,
                                 int* __restrict__ rowptr, int* __restrict__ bsum, int n) {
    __shared__ int s[1024];
    int lid = threadIdx.x;
    int d = blockIdx.x * 1024 + lid;
    int v = 0;
    if (d < n) {
        int c = d / RK_CH;
        int i = d - c * RK_CH;
        size_t base = ((size_t)c * RK_NS) * RK_CH + i;
        unsigned run = 0;
        for (int sl = 0; sl < RK_NS; ++sl) {
            size_t idx = base + (size_t)sl * RK_CH;
            unsigned t = counts16[idx];
            counts16[idx] = (unsigned short)run;
            run += t;
        }
        v = (int)run;
    }
    s[lid] = v;
    __syncthreads();
    #pragma unroll
    for (int off = 1; off < 1024; off <<= 1) {
        int t = (lid >= off) ? s[lid - off] : 0;
        __syncthreads();
        s[lid] += t;
        __syncthreads();
    }
    if (d < n) rowptr[d] = s[lid] - v;
    if (lid == 0) bsum[blockIdx.x] = s[1023];
}

// block 0: exclusive-ize bsum[nb]; block 1: exclusive scan stot[ns] and emit
// the scanned bases into the PADDED cursor array (one per 128B line).
__launch_bounds__(1024)
__global__ void scans2b_kernel(int* __restrict__ bsum, int nb,
                               unsigned* __restrict__ stot,
                               unsigned* __restrict__ cursorp, int ns) {
    __shared__ int s[1024];
    int lid = threadIdx.x;
    if (blockIdx.x == 0) {
        int v = (lid < nb) ? bsum[lid] : 0;
        s[lid] = v;
        __syncthreads();
        #pragma unroll
        for (int off = 1; off < 1024; off <<= 1) {
            int t = (lid >= off) ? s[lid - off] : 0;
            __syncthreads();
            s[lid] += t;
            __syncthreads();
        }
        if (lid < nb) bsum[lid] = s[lid] - v;
    } else {
        int v = (lid < ns) ? (int)stot[lid] : 0;
        s[lid] = v;
        __syncthreads();
        #pragma unroll
        for (int off = 1; off < 1024; off <<= 1) {
            int t = (lid >= off) ? s[lid - off] : 0;
            __syncthreads();
            s[lid] += t;
            __syncthreads();
        }
        if (lid < ns) cursorp[(size_t)lid * CUR_STRIDE] = (unsigned)(s[lid] - v);
    }
}

__global__ void scan3_kernel(int* __restrict__ rowptr, const int* __restrict__ bsum,
                             int n, int nE) {
    int i = blockIdx.x * blockDim.x + threadIdx.x;
    if (i < n) rowptr[i] += bsum[i >> 10];
    if (i == 0) rowptr[n] = nE;
}

// ---------------- two-phase scatter ----------------
// Phase A (full edge grid): each 256-edge block lies in ONE slice (es % 256
// == 0). Compute each edge's FINAL esrc position; append (pos,src) to the
// (chunk,slice) bucket region. Slots via wave-ballot + one leader atomicAdd
// on a line-padded cursor (512 independent serialization domains).
__launch_bounds__(256)
__global__ void bucketize_kernel(const int* __restrict__ src, const int* __restrict__ dst,
                                 const unsigned short* __restrict__ rank16,
                                 const unsigned short* __restrict__ counts16,
                                 const int* __restrict__ rowptr,
                                 unsigned* __restrict__ cursorp,  // padded cursors (destructive)
                                 uint2* __restrict__ bkt,
                                 int nE, int nChunk, int es) {
    int e0   = blockIdx.x * 256;
    int e    = e0 + threadIdx.x;
    int s    = e0 / es;                  // uniform within block
    int lane = threadIdx.x & 63;
    bool valid = e < nE;
    int c = 0, pos = 0, srcv = 0;
    if (valid) {
        int d = dst[e];
        srcv = src[e];
        c = (int)((unsigned)d / RK_CH);
        int i = d - c * RK_CH;
        pos = rowptr[d] + (int)counts16[((size_t)((c << 6) | s)) * RK_CH + i]
                        + (int)rank16[e];
    }
    for (int k = 0; k < nChunk; ++k) {
        unsigned long long mask = __ballot(valid && (c == k));
        if (mask) {
            int leader = __ffsll((long long)mask) - 1;
            unsigned wb = 0;
            if (lane == leader)
                wb = atomicAdd(&cursorp[(size_t)((k << 6) | s) * CUR_STRIDE],
                               (unsigned)__popcll(mask));
            wb = __shfl(wb, leader);
            if (valid && c == k) {
                unsigned slot = wb + (unsigned)__popcll(mask & ((1ull << lane) - 1ull));
                bkt[(size_t)slot] = make_uint2((unsigned)pos, (unsigned)srcv);
            }
        }
    }
}

// Phase B: bid % nChunk == chunk -> all writers of chunk c's esrc window on
// one XCD (round-robin bid->XCD heuristic; correctness mapping-independent).
// Chunk c's bucket region is [rowptr[c*RK_CH], rowptr[min((c+1)*RK_CH, n)]).
__launch_bounds__(256)
__global__ void scatter_b_kernel(const uint2* __restrict__ bkt,
                                 const int* __restrict__ rowptr,
                                 int* __restrict__ esrc, int n, int nChunk, int M) {
    int c = blockIdx.x % nChunk;
    int m = blockIdx.x / nChunk;
    int nlo = c * RK_CH;
    int nhi = (c + 1) * RK_CH; if (nhi > n) nhi = n;
    unsigned lo = (unsigned)rowptr[nlo];
    unsigned hi = (unsigned)rowptr[nhi];
    unsigned csize = hi - lo;
    unsigned seg = (csize + (unsigned)M - 1) / (unsigned)M;
    unsigned b0 = lo + (unsigned)m * seg;
    unsigned b1 = b0 + seg; if (b1 > hi) b1 = hi;
    for (unsigned p = b0 + threadIdx.x; p < b1; p += 256) {
        uint2 pr = bkt[(size_t)p];
        esrc[pr.x] = (int)pr.y;
    }
}

// ---------------- aggregation ----------------
// NOTE (r9/r10): at structural floor (~178MB beyond-L2 traffic). Do not re-tune.

#define ACC8(v) do { \
    s0 += bf_lo((v).x); s1 += bf_hi((v).x); s2 += bf_lo((v).y); s3 += bf_hi((v).y); \
    s4 += bf_lo((v).z); s5 += bf_hi((v).z); s6 += bf_lo((v).w); s7 += bf_hi((v).w); } while (0)

__global__ void aggregate_kernel(const unsigned short* __restrict__ h,
                                 const int* __restrict__ rowptr,
                                 const int* __restrict__ esrc,
                                 unsigned short* __restrict__ agg, int n) {
    int wave = (blockIdx.x * blockDim.x + threadIdx.x) >> 6;
    int lane = threadIdx.x & 63;
    int q    = lane >> 4;           // which node within the wave
    int li   = lane & 15;
    int c0   = li * 8;              // 8 cols owned by this lane
    int node = wave * 4 + q;

    int beg = 0, end = 0;
    if (node < n) { beg = rowptr[node]; end = rowptr[node + 1]; }

    float s0=0.f,s1=0.f,s2=0.f,s3=0.f,s4=0.f,s5=0.f,s6=0.f,s7=0.f;
    int j = beg;
    for (; j + 4 <= end; j += 4) {
        int r0 = esrc[j], r1 = esrc[j + 1], r2 = esrc[j + 2], r3 = esrc[j + 3];
        uint4 v0 = *(const uint4*)&h[(size_t)r0 * 128 + c0];
        uint4 v1 = *(const uint4*)&h[(size_t)r1 * 128 + c0];
        uint4 v2 = *(const uint4*)&h[(size_t)r2 * 128 + c0];
        uint4 v3 = *(const uint4*)&h[(size_t)r3 * 128 + c0];
        ACC8(v0); ACC8(v1); ACC8(v2); ACC8(v3);
    }
    for (; j < end; ++j) {
        int r0 = esrc[j];
        uint4 v0 = *(const uint4*)&h[(size_t)r0 * 128 + c0];
        ACC8(v0);
    }
    if (node < n) {
        int cnt = end - beg;
        float inv = 1.0f / (float)(cnt > 1 ? cnt : 1);
        uint4 o;
        o.x = packbf(s0 * inv, s1 * inv);
        o.y = packbf(s2 * inv, s3 * inv);
        o.z = packbf(s4 * inv, s5 * inv);
        o.w = packbf(s6 * inv, s7 * inv);
        *(uint4*)&agg[(size_t)node * 128 + c0] = o;
    }
}

// ---------------- fused SAGE GEMM via MFMA ----------------

__launch_bounds__(256)
__global__ void sage_gemm_mfma(const unsigned short* __restrict__ A,
                               const unsigned short* __restrict__ H,
                               const unsigned short* __restrict__ Wl,
                               const unsigned short* __restrict__ Wr,
                               const float* __restrict__ bl,
                               unsigned short* __restrict__ out, int n, int relu) {
    int tid  = threadIdx.x;
    int lane = tid & 63;
    int w    = tid >> 6;
    int wm   = w >> 1, wn = w & 1;
    int br   = blockIdx.x * 128 + wm * 64;
    int bc   = wn * 64;
    int lrow = lane & 15;
    int lk   = (lane >> 4) * 8;

    f32x4 acc[4][4] = {};

    #pragma unroll
    for (int half = 0; half < 2; ++half) {
        const unsigned short* X = half ? H : A;
        const unsigned short* W = half ? Wr : Wl;
        const unsigned short* xp[4];
        const unsigned short* wp[4];
        #pragma unroll
        for (int mb = 0; mb < 4; ++mb) {
            int r = br + mb * 16 + lrow;
            if (r >= n) r = n - 1;
            xp[mb] = X + (size_t)r * 128 + lk;
        }
        #pragma unroll
        for (int nb = 0; nb < 4; ++nb)
            wp[nb] = W + (size_t)(bc + nb * 16 + lrow) * 128 + lk;

        #pragma unroll
        for (int ks = 0; ks < 4; ++ks) {
            short8v a[4], b[4];
            #pragma unroll
            for (int mb = 0; mb < 4; ++mb) a[mb] = *(const short8v*)(xp[mb] + ks * 32);
            #pragma unroll
            for (int nb = 0; nb < 4; ++nb) b[nb] = *(const short8v*)(wp[nb] + ks * 32);
            #pragma unroll
            for (int mb = 0; mb < 4; ++mb)
                #pragma unroll
                for (int nb = 0; nb < 4; ++nb)
                    acc[mb][nb] = __builtin_amdgcn_mfma_f32_16x16x32_bf16(
                        a[mb], b[nb], acc[mb][nb], 0, 0, 0);
        }
    }

    int ccol  = lane & 15;
    int crow4 = (lane >> 4) * 4;
    float bv[4];
    #pragma unroll
    for (int nb = 0; nb < 4; ++nb) bv[nb] = bl[bc + nb * 16 + ccol];

    #pragma unroll
    for (int mb = 0; mb < 4; ++mb) {
        #pragma unroll
        for (int r = 0; r < 4; ++r) {
            int row = br + mb * 16 + crow4 + r;
            if (row < n) {
                #pragma unroll
                for (int nb = 0; nb < 4; ++nb) {
                    int col = bc + nb * 16 + ccol;
                    float v = acc[mb][nb][r] + bv[nb];
                    if (relu && v < 0.f) v = 0.f;
                    out[(size_t)row * 128 + col] = f2bf(v);
                }
            }
        }
    }
}

// ---------------- pool + head (fused) ----------------

__device__ __forceinline__ int lbound(const int* __restrict__ a, int n, int v) {
    int lo = 0, hi = n;
    while (lo < hi) { int m = (lo + hi) >> 1; if (a[m] < v) lo = m + 1; else hi = m; }
    return lo;
}

__launch_bounds__(1024)
__global__ void pool_head_kernel(const unsigned short* __restrict__ h,
                                 const int* __restrict__ batch,
                                 const float* __restrict__ Wlin,
                                 const float* __restrict__ blin,
                                 float* __restrict__ out, int n) {
    __shared__ float red[16][128];
    int b  = blockIdx.x;
    int rg = threadIdx.x >> 6;
    int cp = threadIdx.x & 63;
    int lo = lbound(batch, n, b);
    int hi = lbound(batch, n, b + 1);
    float s0 = 0.f, s1 = 0.f;
    for (int i = lo + rg; i < hi; i += 16) {
        unsigned v = *(const unsigned*)&h[(size_t)i * 128 + cp * 2];
        s0 += bf_lo(v); s1 += bf_hi(v);
    }
    red[rg][cp * 2]     = s0;
    red[rg][cp * 2 + 1] = s1;
    __syncthreads();
    #pragma unroll
    for (int off = 8; off >= 1; off >>= 1) {
        if (rg < off) {
            red[rg][cp * 2]     += red[rg + off][cp * 2];
            red[rg][cp * 2 + 1] += red[rg + off][cp * 2 + 1];
        }
        __syncthreads();
    }
    if (threadIdx.x < 32) {
        int j = threadIdx.x;
        int cnt = hi - lo;
        float inv = 1.0f / (float)(cnt > 1 ? cnt : 1);
        const float* wr = &Wlin[(size_t)j * 128];
        float s = 0.f;
        #pragma unroll 4
        for (int c = 0; c < 128; ++c) s += red[0][c] * wr[c];
        out[(size_t)b * 32 + j] = blin[j] + s * inv;
    }
}

extern "C" void kernel_launch(void* const* d_in, const int* in_sizes, int n_in,
                              void* d_out, int out_size, void* d_ws, size_t ws_size,
                              hipStream_t stream) {
    const float* x      = (const float*)d_in[0];
    const int*   eidx   = (const int*)d_in[1];
    const int*   batch  = (const int*)d_in[2];
    const float* Wl[3]  = {(const float*)d_in[3], (const float*)d_in[6], (const float*)d_in[9]};
    const float* bl[3]  = {(const float*)d_in[4], (const float*)d_in[7], (const float*)d_in[10]};
    const float* Wr[3]  = {(const float*)d_in[5], (const float*)d_in[8], (const float*)d_in[11]};
    const float* Wlin   = (const float*)d_in[12];
    const float* blin   = (const float*)d_in[13];
    float* out = (float*)d_out;

    const int N = in_sizes[0] / 128;
    const int E = in_sizes[1] / 2;

    const int* esrc_in = eidx;
    const int* edst_in = eidx + E;

    char* w = (char*)d_ws;
    auto carve = [&](size_t bytes) { char* p = w; w += (bytes + 255) & ~(size_t)255; return p; };
    unsigned short* xbf  = (unsigned short*)carve((size_t)N * 128 * 2);
    unsigned short* hA   = (unsigned short*)carve((size_t)N * 128 * 2);
    unsigned short* hB   = (unsigned short*)carve((size_t)N * 128 * 2);
    unsigned short* agg  = (unsigned short*)carve((size_t)N * 128 * 2);
    unsigned short* Wbf[6];
    for (int i = 0; i < 6; ++i) Wbf[i] = (unsigned short*)carve((size_t)128 * 128 * 2);
    int*   rowptr = (int*)carve((size_t)(N + 1) * 4);
    int*   bsum   = (int*)carve(1024 * 4);
    int*   esrc   = (int*)carve((size_t)E * 4);
    unsigned short* rank16   = (unsigned short*)carve((size_t)E * 2);
    int nChunk = (N + RK_CH - 1) / RK_CH;
    unsigned short* counts16 = (unsigned short*)carve((size_t)nChunk * RK_NS * RK_CH * 2);
    unsigned* stot    = (unsigned*)carve(1024 * 4);                  // raw (c<<6)|s totals
    unsigned* cursorp = (unsigned*)carve((size_t)1024 * CUR_STRIDE * 4); // padded cursors
    uint2*    bkt     = (uint2*)carve((size_t)E * 8);                // (pos, src) staging
    (void)ws_size; (void)n_in;

    // --- fused pre-pass: rank_hist(+stot) | cvt x | cvt weights ---
    int es = (((E + RK_NS - 1) / RK_NS) + 255) & ~255;   // slice size, multiple of 256
    int x4   = N * 128 / 4;
    int cvtB = (x4 + 255) / 256;
    int w4n  = 128 * 128 / 4;
    int w4b  = (w4n + 255) / 256;
    int rhB  = nChunk * RK_NS;
    hipLaunchKernelGGL(pre_kernel, dim3(rhB + cvtB + 6 * w4b), dim3(256), 0, stream,
                       edst_in, rank16, counts16, stot, E, nChunk, es,
                       x, xbf, x4,
                       Wl[0], Wr[0], Wl[1], Wr[1], Wl[2], Wr[2],
                       Wbf[0], Wbf[1], Wbf[2], Wbf[3], Wbf[4], Wbf[5],
                       w4n, w4b);

    // --- offsets + scans + two-phase scatter ---
    int nchunks = (N + 1023) / 1024;
    hipLaunchKernelGGL(seg_scan1_kernel, dim3(nchunks), dim3(1024), 0, stream,
                       counts16, rowptr, bsum, N);
    hipLaunchKernelGGL(scans2b_kernel, dim3(2), dim3(1024), 0, stream,
                       bsum, nchunks, stot, cursorp, nChunk * RK_NS);
    int ngrid = (N + 255) / 256;
    hipLaunchKernelGGL(scan3_kernel, dim3(ngrid), dim3(256), 0, stream, rowptr, bsum, N, E);
    int egrid = (E + 255) / 256;
    hipLaunchKernelGGL(bucketize_kernel, dim3(egrid), dim3(256), 0, stream,
                       esrc_in, edst_in, rank16, counts16, rowptr, cursorp, bkt, E, nChunk, es);
    const int MB = 64;
    hipLaunchKernelGGL(scatter_b_kernel, dim3(nChunk * MB), dim3(256), 0, stream,
                       bkt, rowptr, esrc, N, nChunk, MB);

    // --- 3 SAGE layers ---
    int agrid = (N + 15) / 16;   // 16 nodes per 256-thread block (4 per wave)
    int ggrid = (N + 127) / 128;
    const unsigned short* hin = xbf;
    unsigned short* houts[3] = {hA, hB, hA};
    for (int l = 0; l < 3; ++l) {
        hipLaunchKernelGGL(aggregate_kernel, dim3(agrid), dim3(256), 0, stream,
                           hin, rowptr, esrc, agg, N);
        hipLaunchKernelGGL(sage_gemm_mfma, dim3(ggrid), dim3(256), 0, stream,
                           agg, hin, Wbf[2*l], Wbf[2*l+1], bl[l], houts[l], N, (l < 2) ? 1 : 0);
        hin = houts[l];
    }

    // --- pool + head (fused) ---
    int G = out_size / 32;
    hipLaunchKernelGGL(pool_head_kernel, dim3(G), dim3(1024), 0, stream,
                       hin, batch, Wlin, blin, out, N);
}

// Round 12
// 383.256 us; speedup vs baseline: 1.7772x; 1.0572x over previous
//
#include <hip/hip_runtime.h>
#include <hip/hip_bf16.h>

// ---------------------------------------------------------------------------
// GraphSAGE forward on MI355X — round 15 (revert to round 11, best = 382.8us).
// Post-mortems:
//  * r12-r14 (two-phase scatter): failed 3x for 3 reasons — 2.9% occupancy
//    (r12), cursor line-sharing RMW serialization (r13), ~800K leader-atomic
//    RMWs ~= 70us combined (r14). Pre-commitment honored: scatter2 (~50us,
//    53MB amplified WRITE) is the accepted floor — a random 4B permutation
//    across 8 non-coherent L2s cannot coalesce sectors without paying more
//    in re-scan/atomic cost than the amplification itself.
//  * aggregate x3 (172us): structural floor (8 XCDs x ~86% coverage of h =
//    ~178MB beyond-L2 traffic at ~3.5TB/s service). Two different
//    implementations landed at identical time. Do not re-tune.
// ---------------------------------------------------------------------------

typedef __attribute__((ext_vector_type(8))) short short8v;   // 8 x bf16 (4 VGPRs)
typedef __attribute__((ext_vector_type(4))) float f32x4;

#define RK_CH 12544   // nodes per dst-chunk (50,176 B LDS histogram)
#define RK_NS 64      // edge slices

__device__ __forceinline__ unsigned short f2bf(float f) {
    __hip_bfloat16 h = __float2bfloat16(f);
    return *reinterpret_cast<unsigned short*>(&h);
}
__device__ __forceinline__ float bf_lo(unsigned u) { return __uint_as_float(u << 16); }
__device__ __forceinline__ float bf_hi(unsigned u) { return __uint_as_float(u & 0xffff0000u); }
__device__ __forceinline__ unsigned packbf(float lo, float hi) {
    return ((unsigned)f2bf(hi) << 16) | f2bf(lo);
}

// ---------------- fused pre-pass: rank_hist | cvt(x) | cvt6(weights) -------
// Blocks [0, rhB)              : LDS-histogram rank (chunk c, slice s)
// Blocks [rhB, rhB+cvtB)       : x fp32 -> bf16
// Blocks [rhB+cvtB, +6*w4b)    : 6 weight matrices fp32 -> bf16

__launch_bounds__(256)
__global__ void pre_kernel(const int* __restrict__ dst,
                           unsigned short* __restrict__ rank16,
                           unsigned short* __restrict__ counts16,
                           int nE, int nChunk, int es,
                           const float* __restrict__ x, unsigned short* __restrict__ xbf, int x4,
                           const float* __restrict__ w0, const float* __restrict__ w1,
                           const float* __restrict__ w2, const float* __restrict__ w3,
                           const float* __restrict__ w4, const float* __restrict__ w5,
                           unsigned short* __restrict__ o0, unsigned short* __restrict__ o1,
                           unsigned short* __restrict__ o2, unsigned short* __restrict__ o3,
                           unsigned short* __restrict__ o4, unsigned short* __restrict__ o5,
                           int w4n, int w4b) {
    __shared__ unsigned cnt[RK_CH];
    int rhB  = nChunk * RK_NS;
    int cvtB = (x4 + 255) / 256;
    int bid  = blockIdx.x;

    if (bid < rhB) {
        // ---- rank_hist ----
        int s = bid / nChunk;   // consecutive blocks share the dst slice
        int c = bid % nChunk;
        int lo = c * RK_CH;
        for (int i = threadIdx.x; i < RK_CH; i += 256) cnt[i] = 0u;
        __syncthreads();

        int ebeg = s * es;
        int eend = ebeg + es; if (eend > nE) eend = nE;
        if (ebeg < eend) {
            int nvec = (eend - ebeg) >> 2;   // es multiple of 4, dst 16B-aligned
            for (int g = threadIdx.x; g < nvec; g += 256) {
                int e = ebeg + g * 4;
                int4 d4 = *(const int4*)&dst[e];
                unsigned dc;
                dc = (unsigned)(d4.x - lo);
                if (dc < RK_CH) rank16[e]     = (unsigned short)atomicAdd(&cnt[dc], 1u);
                dc = (unsigned)(d4.y - lo);
                if (dc < RK_CH) rank16[e + 1] = (unsigned short)atomicAdd(&cnt[dc], 1u);
                dc = (unsigned)(d4.z - lo);
                if (dc < RK_CH) rank16[e + 2] = (unsigned short)atomicAdd(&cnt[dc], 1u);
                dc = (unsigned)(d4.w - lo);
                if (dc < RK_CH) rank16[e + 3] = (unsigned short)atomicAdd(&cnt[dc], 1u);
            }
            for (int e = ebeg + (nvec << 2) + threadIdx.x; e < eend; e += 256) {
                unsigned dc = (unsigned)(dst[e] - lo);
                if (dc < RK_CH) rank16[e] = (unsigned short)atomicAdd(&cnt[dc], 1u);
            }
        }
        __syncthreads();
        size_t base = ((size_t)(c * RK_NS + s)) * RK_CH;
        for (int i = threadIdx.x; i < RK_CH; i += 256)
            counts16[base + i] = (unsigned short)cnt[i];
    } else if (bid < rhB + cvtB) {
        // ---- cvt x ----
        int i = (bid - rhB) * 256 + threadIdx.x;
        if (i < x4) {
            float4 v = ((const float4*)x)[i];
            ushort4 o;
            o.x = f2bf(v.x); o.y = f2bf(v.y); o.z = f2bf(v.z); o.w = f2bf(v.w);
            ((ushort4*)xbf)[i] = o;
        }
    } else {
        // ---- cvt6 weights ----
        int idx  = bid - rhB - cvtB;
        int wsel = idx / w4b;
        int wb   = idx % w4b;
        const float* in; unsigned short* out;
        switch (wsel) {
            case 0: in = w0; out = o0; break;
            case 1: in = w1; out = o1; break;
            case 2: in = w2; out = o2; break;
            case 3: in = w3; out = o3; break;
            case 4: in = w4; out = o4; break;
            default: in = w5; out = o5; break;
        }
        int i = wb * 256 + threadIdx.x;
        if (i < w4n) {
            float4 v = ((const float4*)in)[i];
            ushort4 o;
            o.x = f2bf(v.x); o.y = f2bf(v.y); o.z = f2bf(v.z); o.w = f2bf(v.w);
            ((ushort4*)out)[i] = o;
        }
    }
}

// ---------------- seg_offsets + scan1 fused ----------------
// Thread d: exclusive scan over its RK_NS slice counts (in place) -> deg,
// then block-level scan over 1024 degs -> rowptr partial + bsum.

__launch_bounds__(1024)
__global__ void seg_scan1_kernel(unsigned short* __restrict__ counts16,
                                 int* __restrict__ rowptr, int* __restrict__ bsum, int n) {
    __shared__ int s[1024];
    int lid = threadIdx.x;
    int d = blockIdx.x * 1024 + lid;
    int v = 0;
    if (d < n) {
        int c = d / RK_CH;
        int i = d - c * RK_CH;
        size_t base = ((size_t)c * RK_NS) * RK_CH + i;
        unsigned run = 0;
        for (int sl = 0; sl < RK_NS; ++sl) {
            size_t idx = base + (size_t)sl * RK_CH;
            unsigned t = counts16[idx];
            counts16[idx] = (unsigned short)run;
            run += t;
        }
        v = (int)run;
    }
    s[lid] = v;
    __syncthreads();
    #pragma unroll
    for (int off = 1; off < 1024; off <<= 1) {
        int t = (lid >= off) ? s[lid - off] : 0;
        __syncthreads();
        s[lid] += t;
        __syncthreads();
    }
    if (d < n) rowptr[d] = s[lid] - v;
    if (lid == 0) bsum[blockIdx.x] = s[1023];
}

__global__ void scan2_kernel(int* __restrict__ bsum, int nb) {
    __shared__ int s[1024];
    int lid = threadIdx.x;
    int v = (lid < nb) ? bsum[lid] : 0;
    s[lid] = v;
    __syncthreads();
    #pragma unroll
    for (int off = 1; off < 1024; off <<= 1) {
        int t = (lid >= off) ? s[lid - off] : 0;
        __syncthreads();
        s[lid] += t;
        __syncthreads();
    }
    if (lid < nb) bsum[lid] = s[lid] - v;
}

__global__ void scan3_kernel(int* __restrict__ rowptr, const int* __restrict__ bsum,
                             int n, int nE) {
    int i = blockIdx.x * blockDim.x + threadIdx.x;
    if (i < n) rowptr[i] += bsum[i >> 10];
    if (i == 0) rowptr[n] = nE;
}

__global__ void scatter2_kernel(const int* __restrict__ src, const int* __restrict__ dst,
                                const unsigned short* __restrict__ rank16,
                                const unsigned short* __restrict__ counts16,
                                const int* __restrict__ rowptr,
                                int* __restrict__ esrc, int nE, int es) {
    int e = blockIdx.x * blockDim.x + threadIdx.x;
    if (e >= nE) return;
    int d = dst[e];
    int s = e / es;
    int c = d / RK_CH;
    int i = d - c * RK_CH;
    int pos = rowptr[d] + (int)counts16[((size_t)(c * RK_NS + s)) * RK_CH + i]
                        + (int)rank16[e];
    esrc[pos] = src[e];
}

// ---------------- aggregation ----------------
// Quarter-wave per node (4 nodes/wave, 16 nodes/block). Lane li owns cols
// 8*li..8*li+8 and accumulates over ALL of its node's neighbors serially in
// registers — no cross-lane reduction. Row loads stay coalesced (16 lanes x
// 16B = 256B per row). Unroll-4 keeps 16 rows in flight per wave.
// NOTE (r9/r10): at structural floor (~178MB beyond-L2 traffic). Do not re-tune.

#define ACC8(v) do { \
    s0 += bf_lo((v).x); s1 += bf_hi((v).x); s2 += bf_lo((v).y); s3 += bf_hi((v).y); \
    s4 += bf_lo((v).z); s5 += bf_hi((v).z); s6 += bf_lo((v).w); s7 += bf_hi((v).w); } while (0)

__global__ void aggregate_kernel(const unsigned short* __restrict__ h,
                                 const int* __restrict__ rowptr,
                                 const int* __restrict__ esrc,
                                 unsigned short* __restrict__ agg, int n) {
    int wave = (blockIdx.x * blockDim.x + threadIdx.x) >> 6;
    int lane = threadIdx.x & 63;
    int q    = lane >> 4;           // which node within the wave
    int li   = lane & 15;
    int c0   = li * 8;              // 8 cols owned by this lane
    int node = wave * 4 + q;

    int beg = 0, end = 0;
    if (node < n) { beg = rowptr[node]; end = rowptr[node + 1]; }

    float s0=0.f,s1=0.f,s2=0.f,s3=0.f,s4=0.f,s5=0.f,s6=0.f,s7=0.f;
    int j = beg;
    for (; j + 4 <= end; j += 4) {
        int r0 = esrc[j], r1 = esrc[j + 1], r2 = esrc[j + 2], r3 = esrc[j + 3];
        uint4 v0 = *(const uint4*)&h[(size_t)r0 * 128 + c0];
        uint4 v1 = *(const uint4*)&h[(size_t)r1 * 128 + c0];
        uint4 v2 = *(const uint4*)&h[(size_t)r2 * 128 + c0];
        uint4 v3 = *(const uint4*)&h[(size_t)r3 * 128 + c0];
        ACC8(v0); ACC8(v1); ACC8(v2); ACC8(v3);
    }
    for (; j < end; ++j) {
        int r0 = esrc[j];
        uint4 v0 = *(const uint4*)&h[(size_t)r0 * 128 + c0];
        ACC8(v0);
    }
    if (node < n) {
        int cnt = end - beg;
        float inv = 1.0f / (float)(cnt > 1 ? cnt : 1);
        uint4 o;
        o.x = packbf(s0 * inv, s1 * inv);
        o.y = packbf(s2 * inv, s3 * inv);
        o.z = packbf(s4 * inv, s5 * inv);
        o.w = packbf(s6 * inv, s7 * inv);
        *(uint4*)&agg[(size_t)node * 128 + c0] = o;
    }
}

// ---------------- fused SAGE GEMM via MFMA ----------------

__launch_bounds__(256)
__global__ void sage_gemm_mfma(const unsigned short* __restrict__ A,
                               const unsigned short* __restrict__ H,
                               const unsigned short* __restrict__ Wl,
                               const unsigned short* __restrict__ Wr,
                               const float* __restrict__ bl,
                               unsigned short* __restrict__ out, int n, int relu) {
    int tid  = threadIdx.x;
    int lane = tid & 63;
    int w    = tid >> 6;
    int wm   = w >> 1, wn = w & 1;
    int br   = blockIdx.x * 128 + wm * 64;
    int bc   = wn * 64;
    int lrow = lane & 15;
    int lk   = (lane >> 4) * 8;

    f32x4 acc[4][4] = {};

    #pragma unroll
    for (int half = 0; half < 2; ++half) {
        const unsigned short* X = half ? H : A;
        const unsigned short* W = half ? Wr : Wl;
        const unsigned short* xp[4];
        const unsigned short* wp[4];
        #pragma unroll
        for (int mb = 0; mb < 4; ++mb) {
            int r = br + mb * 16 + lrow;
            if (r >= n) r = n - 1;
            xp[mb] = X + (size_t)r * 128 + lk;
        }
        #pragma unroll
        for (int nb = 0; nb < 4; ++nb)
            wp[nb] = W + (size_t)(bc + nb * 16 + lrow) * 128 + lk;

        #pragma unroll
        for (int ks = 0; ks < 4; ++ks) {
            short8v a[4], b[4];
            #pragma unroll
            for (int mb = 0; mb < 4; ++mb) a[mb] = *(const short8v*)(xp[mb] + ks * 32);
            #pragma unroll
            for (int nb = 0; nb < 4; ++nb) b[nb] = *(const short8v*)(wp[nb] + ks * 32);
            #pragma unroll
            for (int mb = 0; mb < 4; ++mb)
                #pragma unroll
                for (int nb = 0; nb < 4; ++nb)
                    acc[mb][nb] = __builtin_amdgcn_mfma_f32_16x16x32_bf16(
                        a[mb], b[nb], acc[mb][nb], 0, 0, 0);
        }
    }

    int ccol  = lane & 15;
    int crow4 = (lane >> 4) * 4;
    float bv[4];
    #pragma unroll
    for (int nb = 0; nb < 4; ++nb) bv[nb] = bl[bc + nb * 16 + ccol];

    #pragma unroll
    for (int mb = 0; mb < 4; ++mb) {
        #pragma unroll
        for (int r = 0; r < 4; ++r) {
            int row = br + mb * 16 + crow4 + r;
            if (row < n) {
                #pragma unroll
                for (int nb = 0; nb < 4; ++nb) {
                    int col = bc + nb * 16 + ccol;
                    float v = acc[mb][nb][r] + bv[nb];
                    if (relu && v < 0.f) v = 0.f;
                    out[(size_t)row * 128 + col] = f2bf(v);
                }
            }
        }
    }
}

// ---------------- pool + head (fused) ----------------

__device__ __forceinline__ int lbound(const int* __restrict__ a, int n, int v) {
    int lo = 0, hi = n;
    while (lo < hi) { int m = (lo + hi) >> 1; if (a[m] < v) lo = m + 1; else hi = m; }
    return lo;
}

__launch_bounds__(1024)
__global__ void pool_head_kernel(const unsigned short* __restrict__ h,
                                 const int* __restrict__ batch,
                                 const float* __restrict__ Wlin,
                                 const float* __restrict__ blin,
                                 float* __restrict__ out, int n) {
    __shared__ float red[16][128];
    int b  = blockIdx.x;
    int rg = threadIdx.x >> 6;
    int cp = threadIdx.x & 63;
    int lo = lbound(batch, n, b);
    int hi = lbound(batch, n, b + 1);
    float s0 = 0.f, s1 = 0.f;
    for (int i = lo + rg; i < hi; i += 16) {
        unsigned v = *(const unsigned*)&h[(size_t)i * 128 + cp * 2];
        s0 += bf_lo(v); s1 += bf_hi(v);
    }
    red[rg][cp * 2]     = s0;
    red[rg][cp * 2 + 1] = s1;
    __syncthreads();
    #pragma unroll
    for (int off = 8; off >= 1; off >>= 1) {
        if (rg < off) {
            red[rg][cp * 2]     += red[rg + off][cp * 2];
            red[rg][cp * 2 + 1] += red[rg + off][cp * 2 + 1];
        }
        __syncthreads();
    }
    if (threadIdx.x < 32) {
        int j = threadIdx.x;
        int cnt = hi - lo;
        float inv = 1.0f / (float)(cnt > 1 ? cnt : 1);
        const float* wr = &Wlin[(size_t)j * 128];
        float s = 0.f;
        #pragma unroll 4
        for (int c = 0; c < 128; ++c) s += red[0][c] * wr[c];
        out[(size_t)b * 32 + j] = blin[j] + s * inv;
    }
}

extern "C" void kernel_launch(void* const* d_in, const int* in_sizes, int n_in,
                              void* d_out, int out_size, void* d_ws, size_t ws_size,
                              hipStream_t stream) {
    const float* x      = (const float*)d_in[0];
    const int*   eidx   = (const int*)d_in[1];
    const int*   batch  = (const int*)d_in[2];
    const float* Wl[3]  = {(const float*)d_in[3], (const float*)d_in[6], (const float*)d_in[9]};
    const float* bl[3]  = {(const float*)d_in[4], (const float*)d_in[7], (const float*)d_in[10]};
    const float* Wr[3]  = {(const float*)d_in[5], (const float*)d_in[8], (const float*)d_in[11]};
    const float* Wlin   = (const float*)d_in[12];
    const float* blin   = (const float*)d_in[13];
    float* out = (float*)d_out;

    const int N = in_sizes[0] / 128;
    const int E = in_sizes[1] / 2;

    const int* esrc_in = eidx;
    const int* edst_in = eidx + E;

    char* w = (char*)d_ws;
    auto carve = [&](size_t bytes) { char* p = w; w += (bytes + 255) & ~(size_t)255; return p; };
    unsigned short* xbf  = (unsigned short*)carve((size_t)N * 128 * 2);
    unsigned short* hA   = (unsigned short*)carve((size_t)N * 128 * 2);
    unsigned short* hB   = (unsigned short*)carve((size_t)N * 128 * 2);
    unsigned short* agg  = (unsigned short*)carve((size_t)N * 128 * 2);
    unsigned short* Wbf[6];
    for (int i = 0; i < 6; ++i) Wbf[i] = (unsigned short*)carve((size_t)128 * 128 * 2);
    int*   rowptr = (int*)carve((size_t)(N + 1) * 4);
    int*   bsum   = (int*)carve(1024 * 4);
    int*   esrc   = (int*)carve((size_t)E * 4);
    unsigned short* rank16   = (unsigned short*)carve((size_t)E * 2);
    int nChunk = (N + RK_CH - 1) / RK_CH;
    unsigned short* counts16 = (unsigned short*)carve((size_t)nChunk * RK_NS * RK_CH * 2);
    (void)ws_size; (void)n_in;

    // --- fused pre-pass: rank_hist | cvt x | cvt weights ---
    int es = (((E + RK_NS - 1) / RK_NS) + 3) & ~3;   // slice size, multiple of 4
    int x4   = N * 128 / 4;
    int cvtB = (x4 + 255) / 256;
    int w4n  = 128 * 128 / 4;
    int w4b  = (w4n + 255) / 256;
    int rhB  = nChunk * RK_NS;
    hipLaunchKernelGGL(pre_kernel, dim3(rhB + cvtB + 6 * w4b), dim3(256), 0, stream,
                       edst_in, rank16, counts16, E, nChunk, es,
                       x, xbf, x4,
                       Wl[0], Wr[0], Wl[1], Wr[1], Wl[2], Wr[2],
                       Wbf[0], Wbf[1], Wbf[2], Wbf[3], Wbf[4], Wbf[5],
                       w4n, w4b);

    // --- offsets + scans + scatter ---
    int nchunks = (N + 1023) / 1024;
    hipLaunchKernelGGL(seg_scan1_kernel, dim3(nchunks), dim3(1024), 0, stream,
                       counts16, rowptr, bsum, N);
    hipLaunchKernelGGL(scan2_kernel, dim3(1), dim3(1024), 0, stream, bsum, nchunks);
    int ngrid = (N + 255) / 256;
    hipLaunchKernelGGL(scan3_kernel, dim3(ngrid), dim3(256), 0, stream, rowptr, bsum, N, E);
    int egrid = (E + 255) / 256;
    hipLaunchKernelGGL(scatter2_kernel, dim3(egrid), dim3(256), 0, stream,
                       esrc_in, edst_in, rank16, counts16, rowptr, esrc, E, es);

    // --- 3 SAGE layers ---
    int agrid = (N + 15) / 16;   // 16 nodes per 256-thread block (4 per wave)
    int ggrid = (N + 127) / 128;
    const unsigned short* hin = xbf;
    unsigned short* houts[3] = {hA, hB, hA};
    for (int l = 0; l < 3; ++l) {
        hipLaunchKernelGGL(aggregate_kernel, dim3(agrid), dim3(256), 0, stream,
                           hin, rowptr, esrc, agg, N);
        hipLaunchKernelGGL(sage_gemm_mfma, dim3(ggrid), dim3(256), 0, stream,
                           agg, hin, Wbf[2*l], Wbf[2*l+1], bl[l], houts[l], N, (l < 2) ? 1 : 0);
        hin = houts[l];
    }

    // --- pool + head (fused) ---
    int G = out_size / 32;
    hipLaunchKernelGGL(pool_head_kernel, dim3(G), dim3(1024), 0, stream,
                       hin, batch, Wlin, blin, out, N);
}